// Round 1
// baseline (218.714 us; speedup 1.0000x reference)
//
#include <hip/hip_runtime.h>
#include <hip/hip_bf16.h>
#include <math.h>

// Problem constants (from reference): B=32, S=1024, H=768, F=128, P=256, NTYPE=7
#define B_    32
#define S_    1024
#define H_    768
#define F_    128
#define P_    256
#define NSEG  129   // F+1 segments; segment 0 (non-field tokens) is dropped

// Output flat offsets (return order: msr, agg, msr_score, dim_score, key, pair, type)
#define OFF_MSR    0          // (32,128,2)  8192
#define OFF_AGG    8192       // (32,128,9)  36864
#define OFF_MSRS   45056      // (32,128,2)  8192
#define OFF_DIM    53248      // (32,128,2)  8192
#define OFF_KEY    61440      // (32,128,2)  8192
#define OFF_PAIR   69632      // (32,256,2)  16384
#define OFF_TYPE   86016      // (32,128,7)  28672

// ---------------- Kernel 1: bucket tokens by (batch, col_id) ----------------
__global__ __launch_bounds__(256) void bucket_kernel(
    const int* __restrict__ col_ids, int* __restrict__ perm,
    int* __restrict__ seg_start)
{
  const int b = blockIdx.x;
  const int tid = threadIdx.x;
  __shared__ int cnt[NSEG];
  __shared__ int base[NSEG + 1];
  for (int i = tid; i < NSEG; i += 256) cnt[i] = 0;
  __syncthreads();
  for (int s = tid; s < S_; s += 256) atomicAdd(&cnt[col_ids[b * S_ + s]], 1);
  __syncthreads();
  if (tid == 0) {
    int acc = 0;
    for (int i = 0; i < NSEG; ++i) { base[i] = acc; acc += cnt[i]; }
    base[NSEG] = acc;  // == S_
  }
  __syncthreads();
  for (int i = tid; i <= NSEG; i += 256) seg_start[b * (NSEG + 1) + i] = base[i];
  for (int i = tid; i < NSEG; i += 256) cnt[i] = 0;
  __syncthreads();
  for (int s = tid; s < S_; s += 256) {
    int seg = col_ids[b * S_ + s];
    int pos = base[seg] + atomicAdd(&cnt[seg], 1);
    perm[b * S_ + pos] = s;
  }
}

// ---------------- Kernel 2: segment mean (gather form) ----------------------
// grid = (F_, B_); block = 192 threads (3 waves), thread t owns floats [4t,4t+3]
__global__ __launch_bounds__(192) void mean_kernel(
    const float* __restrict__ x, const int* __restrict__ perm,
    const int* __restrict__ seg_start, float* __restrict__ fe)
{
  const int f = blockIdx.x;       // field 0..127 -> segment f+1
  const int b = blockIdx.y;
  const int tid = threadIdx.x;
  const int seg = f + 1;
  const int s0 = seg_start[b * (NSEG + 1) + seg];
  const int s1 = seg_start[b * (NSEG + 1) + seg + 1];
  const int cnt = s1 - s0;
  const int* pp = perm + b * S_;

  float4 acc = make_float4(0.f, 0.f, 0.f, 0.f);
  int i = s0;
  int nxt = (i < s1) ? pp[i] : 0;        // software-pipeline the index load
  while (i < s1) {
    const int s = nxt;
    ++i;
    if (i < s1) nxt = pp[i];
    const float4 v = ((const float4*)(x + ((size_t)(b * S_ + s)) * H_))[tid];
    acc.x += v.x; acc.y += v.y; acc.z += v.z; acc.w += v.w;
  }
  const float scale = 1.0f / (float)(cnt > 0 ? cnt : 1);
  acc.x *= scale; acc.y *= scale; acc.z *= scale; acc.w *= scale;
  ((float4*)(fe + ((size_t)(b * F_ + f)) * H_))[tid] = acc;
}

// ---------------- Kernel 3: all heads (wave-per-row) ------------------------
__device__ inline void load12(const float* __restrict__ p, float xv[12]) {
  const float4 a0 = *(const float4*)(p);
  const float4 a1 = *(const float4*)(p + 4);
  const float4 a2 = *(const float4*)(p + 8);
  xv[0] = a0.x; xv[1] = a0.y; xv[2]  = a0.z; xv[3]  = a0.w;
  xv[4] = a1.x; xv[5] = a1.y; xv[6]  = a1.z; xv[7]  = a1.w;
  xv[8] = a2.x; xv[9] = a2.y; xv[10] = a2.z; xv[11] = a2.w;
}

template <int NC>
__device__ inline void accum_head(const float* __restrict__ W, const float xv[12],
                                  int hbase, float acc[NC]) {
#pragma unroll
  for (int k = 0; k < 12; ++k) {
    const float xk = xv[k];
    const float* wr = W + (size_t)(hbase + k) * NC;
#pragma unroll
    for (int c = 0; c < NC; ++c) acc[c] = fmaf(xk, wr[c], acc[c]);
  }
}

template <int NC>
__device__ inline void reduce_wave(float acc[NC]) {
#pragma unroll
  for (int m = 1; m < 64; m <<= 1) {
#pragma unroll
    for (int c = 0; c < NC; ++c) acc[c] += __shfl_xor(acc[c], m, 64);
  }
}

template <int NC>
__device__ inline void write_logsoftmax(const float acc[NC],
                                        const float* __restrict__ bias,
                                        float* __restrict__ out) {
  float v[NC];
  float m = -1e30f;
#pragma unroll
  for (int c = 0; c < NC; ++c) { v[c] = acc[c] + bias[c]; m = fmaxf(m, v[c]); }
  float s = 0.f;
#pragma unroll
  for (int c = 0; c < NC; ++c) s += __expf(v[c] - m);
  const float lse = m + __logf(s);
#pragma unroll
  for (int c = 0; c < NC; ++c) out[c] = v[c] - lse;
}

// blocks [0,1024): field heads, 4 waves/block -> 4096 rows (b*128+f)
// blocks [1024,3072): pair head, 4 waves/block -> 8192 rows (b*256+p)
__global__ __launch_bounds__(256) void heads_kernel(
    const float* __restrict__ fe, const int* __restrict__ pair_idx,
    const float* __restrict__ W_msr,  const float* __restrict__ b_msr,
    const float* __restrict__ W_agg,  const float* __restrict__ b_agg,
    const float* __restrict__ W_dim,  const float* __restrict__ b_dim,
    const float* __restrict__ W_msrs, const float* __restrict__ b_msrs,
    const float* __restrict__ W_key,  const float* __restrict__ b_key,
    const float* __restrict__ W_pair, const float* __restrict__ b_pair,
    const float* __restrict__ W_type, const float* __restrict__ b_type,
    float* __restrict__ out)
{
  const int lane = threadIdx.x & 63;
  const int wave = threadIdx.x >> 6;
  const int hbase = lane * 12;  // lane owns h in [hbase, hbase+12)

  if (blockIdx.x < 1024) {
    const int r = blockIdx.x * 4 + wave;  // 0..4095 == b*128 + f
    float xv[12];
    load12(fe + (size_t)r * H_ + hbase, xv);

    float aMsr[2]  = {0.f, 0.f};
    float aAgg[9]  = {0.f, 0.f, 0.f, 0.f, 0.f, 0.f, 0.f, 0.f, 0.f};
    float aMsrs[2] = {0.f, 0.f};
    float aDim[2]  = {0.f, 0.f};
    float aKey[2]  = {0.f, 0.f};
    float aTyp[7]  = {0.f, 0.f, 0.f, 0.f, 0.f, 0.f, 0.f};

    accum_head<2>(W_msr,  xv, hbase, aMsr);
    accum_head<9>(W_agg,  xv, hbase, aAgg);
    accum_head<2>(W_msrs, xv, hbase, aMsrs);
    accum_head<2>(W_dim,  xv, hbase, aDim);
    accum_head<2>(W_key,  xv, hbase, aKey);
    accum_head<7>(W_type, xv, hbase, aTyp);

    reduce_wave<2>(aMsr);  reduce_wave<9>(aAgg); reduce_wave<2>(aMsrs);
    reduce_wave<2>(aDim);  reduce_wave<2>(aKey); reduce_wave<7>(aTyp);

    if (lane == 0) {
      write_logsoftmax<2>(aMsr,  b_msr,  out + OFF_MSR  + r * 2);
      write_logsoftmax<9>(aAgg,  b_agg,  out + OFF_AGG  + r * 9);
      write_logsoftmax<2>(aMsrs, b_msrs, out + OFF_MSRS + r * 2);
      write_logsoftmax<2>(aDim,  b_dim,  out + OFF_DIM  + r * 2);
      write_logsoftmax<2>(aKey,  b_key,  out + OFF_KEY  + r * 2);
      write_logsoftmax<7>(aTyp,  b_type, out + OFF_TYPE + r * 7);
    }
  } else {
    const int r = (blockIdx.x - 1024) * 4 + wave;  // 0..8191 == b*256 + p
    const int b = r >> 8;
    const int i1 = pair_idx[r * 2 + 0];
    const int i2 = pair_idx[r * 2 + 1];
    float acc[2] = {0.f, 0.f};
    float xv[12];
    load12(fe + ((size_t)(b * F_ + i1)) * H_ + hbase, xv);
    accum_head<2>(W_pair, xv, hbase, acc);                 // rows [0,768)
    load12(fe + ((size_t)(b * F_ + i2)) * H_ + hbase, xv);
    accum_head<2>(W_pair + (size_t)H_ * 2, xv, hbase, acc);  // rows [768,1536)
    reduce_wave<2>(acc);
    if (lane == 0) write_logsoftmax<2>(acc, b_pair, out + OFF_PAIR + r * 2);
  }
}

// ---------------------------------------------------------------------------
extern "C" void kernel_launch(void* const* d_in, const int* in_sizes, int n_in,
                              void* d_out, int out_size, void* d_ws, size_t ws_size,
                              hipStream_t stream) {
  const float* x        = (const float*)d_in[0];   // (32,1024,768) f32
  const int*   col_ids  = (const int*)d_in[1];     // (32,1024) i32
  const int*   pair_idx = (const int*)d_in[2];     // (32,256,2) i32
  // d_in[3] = n_fields (==128, compile-time constant here)
  const float* W_msr  = (const float*)d_in[4];  const float* b_msr  = (const float*)d_in[5];
  const float* W_agg  = (const float*)d_in[6];  const float* b_agg  = (const float*)d_in[7];
  const float* W_dim  = (const float*)d_in[8];  const float* b_dim  = (const float*)d_in[9];
  const float* W_msrs = (const float*)d_in[10]; const float* b_msrs = (const float*)d_in[11];
  const float* W_key  = (const float*)d_in[12]; const float* b_key  = (const float*)d_in[13];
  const float* W_pair = (const float*)d_in[14]; const float* b_pair = (const float*)d_in[15];
  const float* W_type = (const float*)d_in[16]; const float* b_type = (const float*)d_in[17];
  float* out = (float*)d_out;

  // Workspace layout (ws poisoned each call; every byte we use is rewritten):
  //   perm:      B*S ints            = 131072 B
  //   seg_start: B*(NSEG+1) ints     =  16640 B   (total 147712 B, 16B-aligned)
  //   fe:        B*F*H floats        = 12582912 B
  int* perm      = (int*)d_ws;
  int* seg_start = perm + B_ * S_;
  float* fe      = (float*)((char*)d_ws + (size_t)(B_ * S_ + B_ * (NSEG + 1)) * 4);

  bucket_kernel<<<B_, 256, 0, stream>>>(col_ids, perm, seg_start);
  mean_kernel<<<dim3(F_, B_), 192, 0, stream>>>(x, perm, seg_start, fe);
  heads_kernel<<<3072, 256, 0, stream>>>(fe, pair_idx,
                                         W_msr, b_msr, W_agg, b_agg, W_dim, b_dim,
                                         W_msrs, b_msrs, W_key, b_key,
                                         W_pair, b_pair, W_type, b_type, out);
}

// Round 2
// 204.730 us; speedup vs baseline: 1.0683x; 1.0683x over previous
//
#include <hip/hip_runtime.h>
#include <hip/hip_bf16.h>
#include <math.h>

// Problem constants: B=32, S=1024, H=768, F=128, P=256, NTYPE=7
#define B_    32
#define S_    1024
#define H_    768
#define F_    128
#define P_    256
#define NSEG  129   // F+1 segments; segment 0 dropped

// Output flat offsets (return order: msr, agg, msr_score, dim_score, key, pair, type)
#define OFF_MSR    0          // (32,128,2)
#define OFF_AGG    8192       // (32,128,9)
#define OFF_MSRS   45056      // (32,128,2)  msr_score (W_msrs)
#define OFF_DIM    53248      // (32,128,2)  dim_score (W_dim)
#define OFF_KEY    61440      // (32,128,2)
#define OFF_PAIR   69632      // (32,256,2)
#define OFF_TYPE   86016      // (32,128,7)

// Concatenated-transposed W layout (wcat_t[c][h], 24 x 768):
//   c 0-1: W_msr | 2-10: W_agg | 11-12: W_dim | 13-14: W_msrs | 15-16: W_key | 17-23: W_type
#define WCAT_ELEMS  (24 * 768)
#define WPAIR_ELEMS (2 * 1536)

// -------- Kernel 1: bucket tokens by (batch,col_id) + transpose weights -----
// blocks [0,32): bucketing; blocks [32,116): weight transpose into ws
__global__ __launch_bounds__(256) void bucket_prep_kernel(
    const int* __restrict__ col_ids, int* __restrict__ perm,
    int* __restrict__ seg_start,
    const float* __restrict__ W_msr, const float* __restrict__ W_agg,
    const float* __restrict__ W_dim, const float* __restrict__ W_msrs,
    const float* __restrict__ W_key, const float* __restrict__ W_type,
    const float* __restrict__ W_pair,
    float* __restrict__ wcat_t, float* __restrict__ wpair_t)
{
  const int tid = threadIdx.x;
  if (blockIdx.x < B_) {
    const int b = blockIdx.x;
    __shared__ int cnt[NSEG];
    __shared__ int base[NSEG + 1];
    for (int i = tid; i < NSEG; i += 256) cnt[i] = 0;
    __syncthreads();
    for (int s = tid; s < S_; s += 256) atomicAdd(&cnt[col_ids[b * S_ + s]], 1);
    __syncthreads();
    if (tid == 0) {
      int acc = 0;
      for (int i = 0; i < NSEG; ++i) { base[i] = acc; acc += cnt[i]; }
      base[NSEG] = acc;
    }
    __syncthreads();
    for (int i = tid; i <= NSEG; i += 256) seg_start[b * (NSEG + 1) + i] = base[i];
    for (int i = tid; i < NSEG; i += 256) cnt[i] = 0;
    __syncthreads();
    for (int s = tid; s < S_; s += 256) {
      int seg = col_ids[b * S_ + s];
      int pos = base[seg] + atomicAdd(&cnt[seg], 1);
      perm[b * S_ + pos] = s;
    }
  } else {
    const int t = (blockIdx.x - B_) * 256 + tid;
    if (t < WCAT_ELEMS) {
      const int c = t / H_;
      const int h = t - c * H_;
      const float* W; int c0, nc;
      if      (c < 2)  { W = W_msr;  c0 = 0;  nc = 2; }
      else if (c < 11) { W = W_agg;  c0 = 2;  nc = 9; }
      else if (c < 13) { W = W_dim;  c0 = 11; nc = 2; }
      else if (c < 15) { W = W_msrs; c0 = 13; nc = 2; }
      else if (c < 17) { W = W_key;  c0 = 15; nc = 2; }
      else             { W = W_type; c0 = 17; nc = 7; }
      wcat_t[t] = W[h * nc + (c - c0)];
    } else if (t < WCAT_ELEMS + WPAIR_ELEMS) {
      const int u = t - WCAT_ELEMS;
      const int c = u / 1536;
      const int h = u - c * 1536;
      wpair_t[u] = W_pair[h * 2 + c];
    }
  }
}

// -------- Kernel 2: segment mean (gather form) ------------------------------
// grid = (F_, B_); block = 192 threads; thread t owns floats [4t,4t+3]
__global__ __launch_bounds__(192) void mean_kernel(
    const float* __restrict__ x, const int* __restrict__ perm,
    const int* __restrict__ seg_start, float* __restrict__ fe)
{
  const int f = blockIdx.x;   // field -> segment f+1
  const int b = blockIdx.y;
  const int tid = threadIdx.x;
  const int s0 = seg_start[b * (NSEG + 1) + f + 1];
  const int s1 = seg_start[b * (NSEG + 1) + f + 2];
  const int cnt = s1 - s0;
  const int* pp = perm + b * S_;

  float4 acc = make_float4(0.f, 0.f, 0.f, 0.f);
  int i = s0;
  int nxt = (i < s1) ? pp[i] : 0;
  while (i < s1) {
    const int s = nxt;
    ++i;
    if (i < s1) nxt = pp[i];
    const float4 v = ((const float4*)(x + ((size_t)(b * S_ + s)) * H_))[tid];
    acc.x += v.x; acc.y += v.y; acc.z += v.z; acc.w += v.w;
  }
  const float scale = 1.0f / (float)(cnt > 0 ? cnt : 1);
  acc.x *= scale; acc.y *= scale; acc.z *= scale; acc.w *= scale;
  ((float4*)(fe + ((size_t)(b * F_ + f)) * H_))[tid] = acc;
}

// -------- Kernel 3: all heads ----------------------------------------------
template <int NC>
__device__ inline void write_logsoftmax(const float* __restrict__ acc,
                                        const float* __restrict__ bias,
                                        float* __restrict__ out) {
  float v[NC];
  float m = -1e30f;
#pragma unroll
  for (int c = 0; c < NC; ++c) { v[c] = acc[c] + bias[c]; m = fmaxf(m, v[c]); }
  float s = 0.f;
#pragma unroll
  for (int c = 0; c < NC; ++c) s += __expf(v[c] - m);
  const float lse = m + __logf(s);
#pragma unroll
  for (int c = 0; c < NC; ++c) out[c] = v[c] - lse;
}

__device__ inline void write_row(const float a[24], int r,
    const float* __restrict__ b_msr, const float* __restrict__ b_agg,
    const float* __restrict__ b_dim, const float* __restrict__ b_msrs,
    const float* __restrict__ b_key, const float* __restrict__ b_type,
    float* __restrict__ out)
{
  write_logsoftmax<2>(a + 0,  b_msr,  out + OFF_MSR  + r * 2);
  write_logsoftmax<9>(a + 2,  b_agg,  out + OFF_AGG  + r * 9);
  write_logsoftmax<2>(a + 11, b_dim,  out + OFF_DIM  + r * 2);
  write_logsoftmax<2>(a + 13, b_msrs, out + OFF_MSRS + r * 2);
  write_logsoftmax<2>(a + 15, b_key,  out + OFF_KEY  + r * 2);
  write_logsoftmax<7>(a + 17, b_type, out + OFF_TYPE + r * 7);
}

// blocks [0,512): field heads, 4 waves/block, 2 rows/wave -> 4096 rows
// blocks [512,1536): pair head, 4 waves/block, 2 rows/wave -> 8192 rows
__global__ __launch_bounds__(256) void heads_kernel(
    const float* __restrict__ fe, const int* __restrict__ pair_idx,
    const float* __restrict__ wcat_t, const float* __restrict__ wpair_t,
    const float* __restrict__ b_msr, const float* __restrict__ b_agg,
    const float* __restrict__ b_dim, const float* __restrict__ b_msrs,
    const float* __restrict__ b_key, const float* __restrict__ b_pair,
    const float* __restrict__ b_type, float* __restrict__ out)
{
  __shared__ float lds[12 * 768];  // 36 KB (field: one 12-col pass; pair: 3072 used)
  const int tid  = threadIdx.x;
  const int lane = tid & 63;
  const int wave = tid >> 6;

  if (blockIdx.x < 512) {
    const int r0 = (blockIdx.x * 4 + wave) * 2;  // rows r0, r0+1 in [0,4096)
    float4 x0[3], x1[3];
    const float4* p0 = (const float4*)(fe + (size_t)r0 * H_);
    const float4* p1 = (const float4*)(fe + (size_t)(r0 + 1) * H_);
#pragma unroll
    for (int j = 0; j < 3; ++j) { x0[j] = p0[lane + 64 * j]; x1[j] = p1[lane + 64 * j]; }

    float a0[24], a1[24];
#pragma unroll
    for (int c = 0; c < 24; ++c) { a0[c] = 0.f; a1[c] = 0.f; }

    for (int pass = 0; pass < 2; ++pass) {
      __syncthreads();
      const float4* src = (const float4*)(wcat_t + pass * (12 * H_));
      float4* dst = (float4*)lds;
#pragma unroll
      for (int k = 0; k < 9; ++k) dst[tid + 256 * k] = src[tid + 256 * k];
      __syncthreads();
      const float4* w4 = (const float4*)lds;
#pragma unroll
      for (int j = 0; j < 3; ++j) {
#pragma unroll
        for (int c = 0; c < 12; ++c) {
          const float4 w = w4[c * 192 + lane + 64 * j];
          const int cc = pass * 12 + c;
          a0[cc] = fmaf(x0[j].x, w.x, a0[cc]);
          a0[cc] = fmaf(x0[j].y, w.y, a0[cc]);
          a0[cc] = fmaf(x0[j].z, w.z, a0[cc]);
          a0[cc] = fmaf(x0[j].w, w.w, a0[cc]);
          a1[cc] = fmaf(x1[j].x, w.x, a1[cc]);
          a1[cc] = fmaf(x1[j].y, w.y, a1[cc]);
          a1[cc] = fmaf(x1[j].z, w.z, a1[cc]);
          a1[cc] = fmaf(x1[j].w, w.w, a1[cc]);
        }
      }
    }
#pragma unroll
    for (int m = 1; m < 64; m <<= 1) {
#pragma unroll
      for (int c = 0; c < 24; ++c) {
        a0[c] += __shfl_xor(a0[c], m, 64);
        a1[c] += __shfl_xor(a1[c], m, 64);
      }
    }
    if (lane == 0) write_row(a0, r0,     b_msr, b_agg, b_dim, b_msrs, b_key, b_type, out);
    if (lane == 1) write_row(a1, r0 + 1, b_msr, b_agg, b_dim, b_msrs, b_key, b_type, out);
  } else {
    // stage W_pair_t (2 x 1536 = 3072 floats)
    {
      const float4* src = (const float4*)wpair_t;
      float4* dst = (float4*)lds;
#pragma unroll
      for (int k = 0; k < 3; ++k) dst[tid + 256 * k] = src[tid + 256 * k];
    }
    __syncthreads();
    const int r0 = ((blockIdx.x - 512) * 4 + wave) * 2;  // rows in [0,8192)
    const float4* w4 = (const float4*)lds;
    float acc[2][2] = {{0.f, 0.f}, {0.f, 0.f}};
#pragma unroll
    for (int rr = 0; rr < 2; ++rr) {
      const int r = r0 + rr;
      const int b = r >> 8;
      const int i1 = pair_idx[r * 2 + 0];
      const int i2 = pair_idx[r * 2 + 1];
      const float4* q1 = (const float4*)(fe + ((size_t)(b * F_ + i1)) * H_);
      const float4* q2 = (const float4*)(fe + ((size_t)(b * F_ + i2)) * H_);
#pragma unroll
      for (int j = 0; j < 6; ++j) {
        const float4 xv = (j < 3) ? q1[lane + 64 * j] : q2[lane + 64 * (j - 3)];
        const float4 wa = w4[0 * 384 + lane + 64 * j];
        const float4 wb = w4[1 * 384 + lane + 64 * j];
        acc[rr][0] = fmaf(xv.x, wa.x, acc[rr][0]);
        acc[rr][0] = fmaf(xv.y, wa.y, acc[rr][0]);
        acc[rr][0] = fmaf(xv.z, wa.z, acc[rr][0]);
        acc[rr][0] = fmaf(xv.w, wa.w, acc[rr][0]);
        acc[rr][1] = fmaf(xv.x, wb.x, acc[rr][1]);
        acc[rr][1] = fmaf(xv.y, wb.y, acc[rr][1]);
        acc[rr][1] = fmaf(xv.z, wb.z, acc[rr][1]);
        acc[rr][1] = fmaf(xv.w, wb.w, acc[rr][1]);
      }
    }
#pragma unroll
    for (int m = 1; m < 64; m <<= 1) {
#pragma unroll
      for (int rr = 0; rr < 2; ++rr) {
        acc[rr][0] += __shfl_xor(acc[rr][0], m, 64);
        acc[rr][1] += __shfl_xor(acc[rr][1], m, 64);
      }
    }
    if (lane == 0) write_logsoftmax<2>(acc[0], b_pair, out + OFF_PAIR + r0 * 2);
    if (lane == 1) write_logsoftmax<2>(acc[1], b_pair, out + OFF_PAIR + (r0 + 1) * 2);
  }
}

// ---------------------------------------------------------------------------
extern "C" void kernel_launch(void* const* d_in, const int* in_sizes, int n_in,
                              void* d_out, int out_size, void* d_ws, size_t ws_size,
                              hipStream_t stream) {
  const float* x        = (const float*)d_in[0];   // (32,1024,768) f32
  const int*   col_ids  = (const int*)d_in[1];     // (32,1024) i32
  const int*   pair_idx = (const int*)d_in[2];     // (32,256,2) i32
  const float* W_msr  = (const float*)d_in[4];  const float* b_msr  = (const float*)d_in[5];
  const float* W_agg  = (const float*)d_in[6];  const float* b_agg  = (const float*)d_in[7];
  const float* W_dim  = (const float*)d_in[8];  const float* b_dim  = (const float*)d_in[9];
  const float* W_msrs = (const float*)d_in[10]; const float* b_msrs = (const float*)d_in[11];
  const float* W_key  = (const float*)d_in[12]; const float* b_key  = (const float*)d_in[13];
  const float* W_pair = (const float*)d_in[14]; const float* b_pair = (const float*)d_in[15];
  const float* W_type = (const float*)d_in[16]; const float* b_type = (const float*)d_in[17];
  float* out = (float*)d_out;

  // ws layout (every byte rewritten each call):
  //   perm:      B*S ints
  //   seg_start: B*(NSEG+1) ints
  //   fe:        B*F*H floats
  //   wcat_t:    24*768 floats
  //   wpair_t:   2*1536 floats
  int* perm      = (int*)d_ws;
  int* seg_start = perm + B_ * S_;
  float* fe      = (float*)(seg_start + B_ * (NSEG + 1));
  float* wcat_t  = fe + (size_t)B_ * F_ * H_;
  float* wpair_t = wcat_t + WCAT_ELEMS;

  bucket_prep_kernel<<<B_ + 84, 256, 0, stream>>>(
      col_ids, perm, seg_start,
      W_msr, W_agg, W_dim, W_msrs, W_key, W_type, W_pair, wcat_t, wpair_t);
  mean_kernel<<<dim3(F_, B_), 192, 0, stream>>>(x, perm, seg_start, fe);
  heads_kernel<<<1536, 256, 0, stream>>>(fe, pair_idx, wcat_t, wpair_t,
                                         b_msr, b_agg, b_dim, b_msrs, b_key,
                                         b_pair, b_type, out);
}